// Round 1
// baseline (211.219 us; speedup 1.0000x reference)
//
#include <hip/hip_runtime.h>
#include <math.h>

#define N_TOK 2048          // tokens per modality (64*32)
#define NMOD  3
#define NTOT  6144          // N_TOK * NMOD
#define D     256
#define INV_TAU 10.0f

#define BM 128              // block tile (rows == cols)
#define BK 32               // k-step
#define LSTR 132            // padded LDS row stride (words), 132*4=528B ≡ 0 mod 16

// ---------------------------------------------------------------- normalize
__global__ void norm_kernel(const float* __restrict__ a,
                            const float* __restrict__ b,
                            const float* __restrict__ c,
                            float* __restrict__ fn) {
    int row = blockIdx.x;
    const float* src;
    if (row < N_TOK)            src = a + (size_t)row * D;
    else if (row < 2 * N_TOK)   src = b + (size_t)(row - N_TOK) * D;
    else                        src = c + (size_t)(row - 2 * N_TOK) * D;

    int t = threadIdx.x;                 // 256 threads, one element each
    float v = src[t];
    float ss = v * v;
    #pragma unroll
    for (int o = 32; o > 0; o >>= 1) ss += __shfl_down(ss, o, 64);
    __shared__ float red[4];
    int lane = t & 63, w = t >> 6;
    if (lane == 0) red[w] = ss;
    __syncthreads();
    float tot = red[0] + red[1] + red[2] + red[3];
    float inv = rsqrtf(fmaxf(tot, 1e-16f));   // norms*norms clipped at 1e-8 in ref; never active here
    fn[(size_t)row * D + t] = v * inv;
}

// -------------------------------------------------- misaligned-by-1 store of 8 floats
// p points to d_out+1 + r*6144 + c with c % 4 == 0  ->  byte addr ≡ 4 (mod 16)
__device__ __forceinline__ void store8(float* p, const float v[8]) {
    p[0] = v[0];
    *reinterpret_cast<float2*>(p + 1) = make_float2(v[1], v[2]);
    *reinterpret_cast<float4*>(p + 3) = make_float4(v[3], v[4], v[5], v[6]);
    p[7] = v[7];
}

// ---------------------------------------------------------------- symmetric GEMM
// C = F * F^T, F: [NTOT][D] row-major (normalized feats). Only br<=bc computed,
// mirror tile stored for br<bc.
__global__ __launch_bounds__(256, 2)
void gemm_sym(const float* __restrict__ F, float* __restrict__ C) {
    int bc = blockIdx.x, br = blockIdx.y;
    if (br > bc) return;

    __shared__ float As[BK][LSTR];
    __shared__ float Bs[BK][LSTR];

    const int rowBase = br * BM;
    const int colBase = bc * BM;
    const int t  = threadIdx.x;
    const int tx = t & 15;          // 16 cols of threads
    const int ty = t >> 4;          // 16 rows of threads

    float acc[8][8] = {};

    for (int kk = 0; kk < D; kk += BK) {
        // stage both tiles, k-major in LDS (transpose via scalar writes)
        #pragma unroll
        for (int i = 0; i < 4; ++i) {
            int f  = t + i * 256;        // 0..1023
            int r  = f >> 3;             // 0..127
            int k4 = (f & 7) << 2;       // 0,4,...,28
            float4 av = *reinterpret_cast<const float4*>(&F[(size_t)(rowBase + r) * D + kk + k4]);
            As[k4 + 0][r] = av.x; As[k4 + 1][r] = av.y;
            As[k4 + 2][r] = av.z; As[k4 + 3][r] = av.w;
            float4 bv = *reinterpret_cast<const float4*>(&F[(size_t)(colBase + r) * D + kk + k4]);
            Bs[k4 + 0][r] = bv.x; Bs[k4 + 1][r] = bv.y;
            Bs[k4 + 2][r] = bv.z; Bs[k4 + 3][r] = bv.w;
        }
        __syncthreads();

        #pragma unroll 4
        for (int k = 0; k < BK; ++k) {
            float av[8], bv[8];
            *reinterpret_cast<float4*>(&av[0]) = *reinterpret_cast<const float4*>(&As[k][ty * 8]);
            *reinterpret_cast<float4*>(&av[4]) = *reinterpret_cast<const float4*>(&As[k][ty * 8 + 4]);
            *reinterpret_cast<float4*>(&bv[0]) = *reinterpret_cast<const float4*>(&Bs[k][tx * 8]);
            *reinterpret_cast<float4*>(&bv[4]) = *reinterpret_cast<const float4*>(&Bs[k][tx * 8 + 4]);
            #pragma unroll
            for (int i = 0; i < 8; ++i)
                #pragma unroll
                for (int j = 0; j < 8; ++j)
                    acc[i][j] = fmaf(av[i], bv[j], acc[i][j]);
        }
        __syncthreads();
    }

    // direct tile
    #pragma unroll
    for (int i = 0; i < 8; ++i) {
        int r = rowBase + ty * 8 + i;
        store8(&C[(size_t)r * NTOT + colBase + tx * 8], acc[i]);
    }
    // mirror tile (transpose)
    if (br != bc) {
        #pragma unroll
        for (int j = 0; j < 8; ++j) {
            float vt[8];
            #pragma unroll
            for (int i = 0; i < 8; ++i) vt[i] = acc[i][j];
            int r = colBase + tx * 8 + j;
            store8(&C[(size_t)r * NTOT + rowBase + ty * 8], vt);
        }
    }
}

// ---------------------------------------------------------------- per-row loss
__global__ void loss_rows(const float* __restrict__ C, float* __restrict__ rowloss) {
    int r = blockIdx.x;
    const float* row = C + (size_t)r * NTOT;
    int t = threadIdx.x;
    float s = 0.0f;
    for (int j = t; j < NTOT; j += 256) {
        if (j != r) s += __expf(row[j] * INV_TAU);
    }
    #pragma unroll
    for (int o = 32; o > 0; o >>= 1) s += __shfl_down(s, o, 64);
    __shared__ float red[4];
    int lane = t & 63, w = t >> 6;
    if (lane == 0) red[w] = s;
    __syncthreads();
    if (t == 0) {
        float tot = red[0] + red[1] + red[2] + red[3];
        float lse = __logf(tot);
        int k = r / N_TOK, i = r % N_TOK;
        float ps = 0.0f;
        #pragma unroll
        for (int j = 0; j < NMOD; ++j)
            if (j != k) ps += __expf(row[i + j * N_TOK] * INV_TAU);
        rowloss[r] = lse - __logf(ps);
    }
}

// ---------------------------------------------------------------- final reduce
__global__ void final_reduce(const float* __restrict__ rowloss, float* __restrict__ out) {
    int t = threadIdx.x;
    float s = 0.0f;
    for (int j = t; j < NTOT; j += 256) s += rowloss[j];
    #pragma unroll
    for (int o = 32; o > 0; o >>= 1) s += __shfl_down(s, o, 64);
    __shared__ float red[4];
    int lane = t & 63, w = t >> 6;
    if (lane == 0) red[w] = s;
    __syncthreads();
    if (t == 0) out[0] = (red[0] + red[1] + red[2] + red[3]) / (float)NTOT;
}

// ---------------------------------------------------------------- launch
extern "C" void kernel_launch(void* const* d_in, const int* in_sizes, int n_in,
                              void* d_out, int out_size, void* d_ws, size_t ws_size,
                              hipStream_t stream) {
    const float* aerial = (const float*)d_in[0];
    const float* s2     = (const float*)d_in[1];
    const float* s1     = (const float*)d_in[2];
    float* out = (float*)d_out;

    float* fn      = (float*)d_ws;                 // 6144*256 fp32 normalized feats
    float* rowloss = fn + (size_t)NTOT * D;        // 6144 fp32
    float* C       = out + 1;                      // logits, row-major 6144x6144

    norm_kernel<<<NTOT, 256, 0, stream>>>(aerial, s2, s1, fn);

    dim3 grid(NTOT / BM, NTOT / BM);               // 48x48, lower-tri blocks early-exit
    gemm_sym<<<grid, 256, 0, stream>>>(fn, C);

    loss_rows<<<NTOT, 256, 0, stream>>>(C, rowloss);
    final_reduce<<<1, 256, 0, stream>>>(rowloss, out);
}

// Round 2
// 60.131 us; speedup vs baseline: 3.5127x; 3.5127x over previous
//
#include <hip/hip_runtime.h>
#include <math.h>

#define N_TOK 2048          // tokens per modality (64*32)
#define NMOD  3
#define NTOT  6144          // N_TOK * NMOD
#define D     256
#define INV_TAU 10.0f

#define BM 128              // output tile (rows == cols)
#define BK 64               // k-step (64 bf16 = 128 B rows -> 8x16B swizzle slots)
#define NBLK (NTOT / BM)    // 48

typedef float  f32x4  __attribute__((ext_vector_type(4)));
typedef short  bf16x8 __attribute__((ext_vector_type(8)));

// ------------------------------------------------------------- helpers
__device__ __forceinline__ unsigned short f2bf(float x) {
    unsigned int u = __float_as_uint(x);
    unsigned int r = (u + 0x7fffu + ((u >> 16) & 1u)) >> 16;   // RNE
    return (unsigned short)r;
}

__device__ __forceinline__ void gload16(const void* g, void* s) {
    __builtin_amdgcn_global_load_lds(
        (const __attribute__((address_space(1))) void*)g,
        (__attribute__((address_space(3))) void*)s, 16, 0, 0);
}

// ------------------------------------------------------------- normalize + bf16
__global__ void norm_kernel(const float* __restrict__ a,
                            const float* __restrict__ b,
                            const float* __restrict__ c,
                            unsigned short* __restrict__ H) {
    int row = blockIdx.x;
    const float* src;
    if (row < N_TOK)            src = a + (size_t)row * D;
    else if (row < 2 * N_TOK)   src = b + (size_t)(row - N_TOK) * D;
    else                        src = c + (size_t)(row - 2 * N_TOK) * D;

    int t = threadIdx.x;                 // 256 threads, one element each
    float v = src[t];
    float ss = v * v;
    #pragma unroll
    for (int o = 32; o > 0; o >>= 1) ss += __shfl_down(ss, o, 64);
    __shared__ float red[4];
    int lane = t & 63, w = t >> 6;
    if (lane == 0) red[w] = ss;
    __syncthreads();
    float tot = red[0] + red[1] + red[2] + red[3];
    float inv = rsqrtf(fmaxf(tot, 1e-16f));
    H[(size_t)row * D + t] = f2bf(v * inv);
}

// ------------------------------------------------------------- bf16 MFMA GEMM, fused exp-rowsum
// C = F F^T (F = normalized feats, bf16). Full grid 48x48. Each block 128x128,
// 4 waves of 64x64, acc 4x4 frags of mfma_f32_16x16x32_bf16.
// Epilogue: stores C tile (fp32, misalign-tolerant scalar stores) and writes
// partials[bc][row] = sum_j-in-tile exp(10*C[row][j]) (diag excluded).
__global__ __launch_bounds__(256)
void gemm_bf16(const unsigned short* __restrict__ H,
               float* __restrict__ C,
               float* __restrict__ partials) {
    const int bc = blockIdx.x, br = blockIdx.y;
    __shared__ unsigned short As[BM * BK];    // 16 KB, XOR-swizzled 16B slots
    __shared__ unsigned short Bs[BM * BK];    // 16 KB
    __shared__ float rowsum[BM][2];

    const int t    = threadIdx.x;
    const int lane = t & 63;
    const int w    = t >> 6;      // wave id 0..3
    const int wm   = w >> 1;      // 0..1
    const int wn   = w & 1;       // 0..1

    f32x4 acc[4][4] = {};

    const unsigned short* Abase = H + (size_t)(br * BM) * D;
    const unsigned short* Bbase = H + (size_t)(bc * BM) * D;

    for (int kk = 0; kk < D; kk += BK) {
        // ---- stage A,B tiles: linear LDS dest, inverse-swizzled global src
        #pragma unroll
        for (int i = 0; i < 4; ++i) {
            int ch   = w * 4 + i;                 // 0..15 (1 KB chunks)
            int row  = ch * 8 + (lane >> 3);      // 0..127
            int slot = (lane & 7) ^ (row & 7);    // involution
            gload16(Abase + (size_t)row * D + kk + slot * 8,
                    (unsigned short*)As + ch * 512);
            gload16(Bbase + (size_t)row * D + kk + slot * 8,
                    (unsigned short*)Bs + ch * 512);
        }
        __syncthreads();

        // ---- compute: 2 k-halves of 32
        #pragma unroll
        for (int kh = 0; kh < 2; ++kh) {
            bf16x8 a[4], b[4];
            #pragma unroll
            for (int m = 0; m < 4; ++m) {
                int row  = wm * 64 + m * 16 + (lane & 15);
                int slot = (kh * 4 + (lane >> 4)) ^ (row & 7);
                a[m] = *(const bf16x8*)&As[row * 64 + slot * 8];
            }
            #pragma unroll
            for (int n = 0; n < 4; ++n) {
                int row  = wn * 64 + n * 16 + (lane & 15);
                int slot = (kh * 4 + (lane >> 4)) ^ (row & 7);
                b[n] = *(const bf16x8*)&Bs[row * 64 + slot * 8];
            }
            #pragma unroll
            for (int m = 0; m < 4; ++m)
                #pragma unroll
                for (int n = 0; n < 4; ++n)
                    acc[m][n] = __builtin_amdgcn_mfma_f32_16x16x32_bf16(
                        a[m], b[n], acc[m][n], 0, 0, 0);
        }
        __syncthreads();
    }

    // ---- epilogue: store C + per-row exp sums
    const int gr0 = br * BM, gc0 = bc * BM;
    float rs[4][4];   // [m][j] row partials across this lane's 4 cols x 4 n-frags
    #pragma unroll
    for (int m = 0; m < 4; ++m)
        #pragma unroll
        for (int j = 0; j < 4; ++j) rs[m][j] = 0.0f;

    #pragma unroll
    for (int m = 0; m < 4; ++m) {
        #pragma unroll
        for (int n = 0; n < 4; ++n) {
            #pragma unroll
            for (int j = 0; j < 4; ++j) {
                int rl = wm * 64 + m * 16 + (lane >> 4) * 4 + j;
                int cl = wn * 64 + n * 16 + (lane & 15);
                float v = acc[m][n][j];
                C[(size_t)(gr0 + rl) * NTOT + gc0 + cl] = v;
                float e = __expf(v * INV_TAU);
                if (gr0 + rl == gc0 + cl) e = 0.0f;   // mask diagonal
                rs[m][j] += e;
            }
        }
    }
    // reduce across the 16 lanes sharing (lane>>4): xor over lane bits 0..3
    #pragma unroll
    for (int m = 0; m < 4; ++m)
        #pragma unroll
        for (int j = 0; j < 4; ++j) {
            float s = rs[m][j];
            s += __shfl_xor(s, 1, 64);
            s += __shfl_xor(s, 2, 64);
            s += __shfl_xor(s, 4, 64);
            s += __shfl_xor(s, 8, 64);
            rs[m][j] = s;
        }
    if ((lane & 15) == 0) {
        #pragma unroll
        for (int m = 0; m < 4; ++m)
            #pragma unroll
            for (int j = 0; j < 4; ++j)
                rowsum[wm * 64 + m * 16 + (lane >> 4) * 4 + j][wn] = rs[m][j];
    }
    __syncthreads();
    if (t < BM)
        partials[(size_t)bc * NTOT + gr0 + t] = rowsum[t][0] + rowsum[t][1];
}

// ------------------------------------------------------------- combine per-row
__global__ void loss_combine(const float* __restrict__ C,
                             const float* __restrict__ partials,
                             float* __restrict__ blocksum) {
    int r = blockIdx.x * 256 + threadIdx.x;   // 24 blocks x 256
    float s = 0.0f;
    #pragma unroll 8
    for (int b = 0; b < NBLK; ++b) s += partials[(size_t)b * NTOT + r];

    int k = r >> 11;          // r / 2048
    int i = r & 2047;
    float ps = 0.0f;
    #pragma unroll
    for (int j = 0; j < NMOD; ++j)
        if (j != k) ps += __expf(INV_TAU * C[(size_t)r * NTOT + i + j * N_TOK]);

    float rl = __logf(s) - __logf(ps);

    // block reduce
    #pragma unroll
    for (int o = 32; o > 0; o >>= 1) rl += __shfl_down(rl, o, 64);
    __shared__ float red[4];
    int lane = threadIdx.x & 63, w = threadIdx.x >> 6;
    if (lane == 0) red[w] = rl;
    __syncthreads();
    if (threadIdx.x == 0)
        blocksum[blockIdx.x] = red[0] + red[1] + red[2] + red[3];
}

__global__ void final_sum(const float* __restrict__ blocksum, float* __restrict__ out) {
    int t = threadIdx.x;   // 64 threads
    float s = (t < 24) ? blocksum[t] : 0.0f;
    #pragma unroll
    for (int o = 32; o > 0; o >>= 1) s += __shfl_down(s, o, 64);
    if (t == 0) out[0] = s / (float)NTOT;
}

// ------------------------------------------------------------- launch
extern "C" void kernel_launch(void* const* d_in, const int* in_sizes, int n_in,
                              void* d_out, int out_size, void* d_ws, size_t ws_size,
                              hipStream_t stream) {
    const float* aerial = (const float*)d_in[0];
    const float* s2     = (const float*)d_in[1];
    const float* s1     = (const float*)d_in[2];
    float* out = (float*)d_out;

    unsigned short* H   = (unsigned short*)d_ws;                 // 6144*256 bf16 = 3 MB
    float* partials     = (float*)((char*)d_ws + (size_t)NTOT * D * 2);  // [48][6144] f32
    float* blocksum     = partials + (size_t)NBLK * NTOT;        // 24 floats
    float* C            = out + 1;                               // logits 6144x6144

    norm_kernel<<<NTOT, 256, 0, stream>>>(aerial, s2, s1, H);

    dim3 grid(NBLK, NBLK);
    gemm_bf16<<<grid, 256, 0, stream>>>(H, C, partials);

    loss_combine<<<NTOT / 256, 256, 0, stream>>>(C, partials, blocksum);
    final_sum<<<1, 64, 0, stream>>>(blocksum, out);
}